// Round 2
// baseline (265.970 us; speedup 1.0000x reference)
//
#include <hip/hip_runtime.h>
#include <math.h>

#define BB 1024
#define NN 1024
#define DD 64
#define MARGIN_V 0.5f
#define EPS_V 1e-6f
#define QSPLIT 4               // blocks per batch row in k_dist
#define QCOLS (NN / QSPLIT)    // 256 columns per block

// ---------------------------------------------------------------------------
// Kernel 1: 4096 blocks = 4 per batch row (quarter q covers cols [q*256,+256)).
//   256 threads = 4 waves; 16 lane-groups of 16; group handles 16 columns.
//   Unroll-by-2: 6 float4 loads hoisted, two independent shfl chains
//   interleaved. Partials written per (b,q) to ws.
// ---------------------------------------------------------------------------
__global__ __launch_bounds__(256) void k_dist(const float* __restrict__ a,
                                              const float* __restrict__ p,
                                              const float* __restrict__ g,
                                              float* __restrict__ ws_loss,
                                              float* __restrict__ ws_score,
                                              int* __restrict__ ws_idx,
                                              int* __restrict__ ws_valid)
{
    const int blk  = blockIdx.x;       // 0..4095
    const int b    = blk >> 2;
    const int q    = blk & 3;
    const int tid  = threadIdx.x;
    const int lane = tid & 63;
    const int wave = tid >> 6;         // 0..3
    const int grp  = lane >> 4;        // 0..3
    const int gl   = lane & 15;        // lane within 16-lane group
    const int group = wave * 4 + grp;  // 0..15

    const size_t base  = (size_t)b * (NN * DD);
    const int    ncol0 = q * QCOLS + group;

    float loss_acc   = 0.f;
    float best_score = -INFINITY;
    int   best_idx   = 0;
    int   any_valid  = 0;

    // 16 columns per group: n = ncol0 + i*16, i = 0..15; unrolled 2x
    for (int j = 0; j < 8; ++j) {
        const int n0 = ncol0 + j * 32;
        const int n1 = n0 + 16;
        const size_t off0 = base + (size_t)n0 * DD + (size_t)gl * 4;
        const size_t off1 = off0 + (size_t)16 * DD;

        const float4 va0 = *(const float4*)(a + off0);
        const float4 vp0 = *(const float4*)(p + off0);
        const float4 vg0 = *(const float4*)(g + off0);
        const float4 va1 = *(const float4*)(a + off1);
        const float4 vp1 = *(const float4*)(p + off1);
        const float4 vg1 = *(const float4*)(g + off1);

        float dp0 = 0.f, dn0 = 0.f, dp1 = 0.f, dn1 = 0.f, t;
        t = va0.x - vp0.x + EPS_V; dp0 += t * t;
        t = va0.y - vp0.y + EPS_V; dp0 += t * t;
        t = va0.z - vp0.z + EPS_V; dp0 += t * t;
        t = va0.w - vp0.w + EPS_V; dp0 += t * t;
        t = va0.x - vg0.x + EPS_V; dn0 += t * t;
        t = va0.y - vg0.y + EPS_V; dn0 += t * t;
        t = va0.z - vg0.z + EPS_V; dn0 += t * t;
        t = va0.w - vg0.w + EPS_V; dn0 += t * t;
        t = va1.x - vp1.x + EPS_V; dp1 += t * t;
        t = va1.y - vp1.y + EPS_V; dp1 += t * t;
        t = va1.z - vp1.z + EPS_V; dp1 += t * t;
        t = va1.w - vp1.w + EPS_V; dp1 += t * t;
        t = va1.x - vg1.x + EPS_V; dn1 += t * t;
        t = va1.y - vg1.y + EPS_V; dn1 += t * t;
        t = va1.z - vg1.z + EPS_V; dn1 += t * t;
        t = va1.w - vg1.w + EPS_V; dn1 += t * t;

        // interleaved butterflies over the 16-lane group (independent chains)
        for (int m = 1; m < 16; m <<= 1) {
            dp0 += __shfl_xor(dp0, m, 64);
            dn0 += __shfl_xor(dn0, m, 64);
            dp1 += __shfl_xor(dp1, m, 64);
            dn1 += __shfl_xor(dn1, m, 64);
        }

        if (gl == 0) {
            {
                const float dist_pos = sqrtf(dp0);
                const float dist_neg = sqrtf(dn0);
                const float diff = MARGIN_V + dist_pos - dist_neg;
                loss_acc += fmaxf(diff, 0.f);
                const bool valid = diff > 0.f;
                any_valid |= (int)valid;
                const float score = valid ? dist_neg : -INFINITY;
                if (score > best_score) { best_score = score; best_idx = n0; }
            }
            {
                const float dist_pos = sqrtf(dp1);
                const float dist_neg = sqrtf(dn1);
                const float diff = MARGIN_V + dist_pos - dist_neg;
                loss_acc += fmaxf(diff, 0.f);
                const bool valid = diff > 0.f;
                any_valid |= (int)valid;
                const float score = valid ? dist_neg : -INFINITY;
                if (score > best_score) { best_score = score; best_idx = n1; }
            }
        }
    }

    __shared__ float s_score[16];
    __shared__ int   s_idx[16];
    __shared__ float s_loss[16];
    __shared__ int   s_valid[16];
    if (gl == 0) {
        s_score[group] = best_score;
        s_idx[group]   = best_idx;
        s_loss[group]  = loss_acc;
        s_valid[group] = any_valid;
    }
    __syncthreads();
    if (tid == 0) {
        float bs = s_score[0]; int bi = s_idx[0];
        float ls = s_loss[0];  int av = s_valid[0];
        for (int k = 1; k < 16; ++k) {
            const float sc = s_score[k]; const int ix = s_idx[k];
            if (sc > bs || (sc == bs && ix < bi)) { bs = sc; bi = ix; }
            ls += s_loss[k];
            av |= s_valid[k];
        }
        ws_loss[blk]  = ls;
        ws_score[blk] = bs;
        ws_idx[blk]   = bi;
        ws_valid[blk] = av;
    }
}

// ---------------------------------------------------------------------------
// Kernel 2 (single block, 1024 threads): thread b merges its 4 quarter
// partials (first-index tie-break), writes sel/has_valid, then block-reduces
// the loss sum -> out[0] = mean.
// ---------------------------------------------------------------------------
__global__ __launch_bounds__(1024) void k_merge(const float* __restrict__ ws_loss,
                                                const float* __restrict__ ws_score,
                                                const int* __restrict__ ws_idx,
                                                const int* __restrict__ ws_valid,
                                                float* __restrict__ out_loss,
                                                int* __restrict__ ws_sel,
                                                float* __restrict__ out_hasvalid)
{
    const int b = threadIdx.x;
    float ls = 0.f;
    float bs = -INFINITY;
    int   bi = 0x7fffffff;
    int   av = 0;
    for (int qq = 0; qq < QSPLIT; ++qq) {
        const int idx = b * QSPLIT + qq;
        const float sc = ws_score[idx];
        const int   ix = ws_idx[idx];
        if (sc > bs || (sc == bs && ix < bi)) { bs = sc; bi = ix; }
        ls += ws_loss[idx];
        av |= ws_valid[idx];
    }
    ws_sel[b] = bi;
    out_hasvalid[b] = av ? 1.0f : 0.0f;

    // block reduce of ls over 1024 threads
    __shared__ float s[16];
    float v = ls;
    for (int m = 1; m < 64; m <<= 1) v += __shfl_xor(v, m, 64);
    if ((b & 63) == 0) s[b >> 6] = v;
    __syncthreads();
    if (b == 0) {
        float tot = 0.f;
        for (int k = 0; k < 16; ++k) tot += s[k];
        out_loss[0] = tot / (float)((size_t)BB * NN);
    }
}

// ---------------------------------------------------------------------------
// Kernel 3: hard_neg[b] = negative[sel_col[b]]  (N*D = 65536 floats per b).
// Dest (out+1) is 4B-misaligned vs 16B -> scalar float copies (256B/wave-instr,
// fully coalesced).
// ---------------------------------------------------------------------------
__global__ __launch_bounds__(256) void k_gather(const float* __restrict__ g,
                                                const int* __restrict__ ws_sel,
                                                float* __restrict__ out_hn)
{
    const int b   = blockIdx.y;
    const int sel = ws_sel[b];
    const float* __restrict__ src = g      + (size_t)sel * (NN * DD);
    float* __restrict__       dst = out_hn + (size_t)b   * (NN * DD);
    const int t = blockIdx.x * blockDim.x + threadIdx.x;   // 0..8191
    #pragma unroll
    for (int k = 0; k < (NN * DD) / 8192; ++k) {
        const int idx = t + k * 8192;
        dst[idx] = src[idx];
    }
}

extern "C" void kernel_launch(void* const* d_in, const int* in_sizes, int n_in,
                              void* d_out, int out_size, void* d_ws, size_t ws_size,
                              hipStream_t stream) {
    const float* anchor   = (const float*)d_in[0];
    const float* positive = (const float*)d_in[1];
    const float* negative = (const float*)d_in[2];
    float* out = (float*)d_out;

    // out layout: [0] loss | [1 .. 1+B*N*D) hard_neg | [1+B*N*D .. +B) has_valid
    float* out_loss     = out;
    float* out_hard_neg = out + 1;
    float* out_hasvalid = out + 1 + (size_t)BB * NN * DD;

    // ws layout: 4096 loss | 4096 score | 4096 idx | 4096 valid | 1024 sel
    float* ws_loss  = (float*)d_ws;
    float* ws_score = ws_loss + BB * QSPLIT;
    int*   ws_idx   = (int*)(ws_score + BB * QSPLIT);
    int*   ws_valid = ws_idx + BB * QSPLIT;
    int*   ws_sel   = ws_valid + BB * QSPLIT;

    k_dist<<<dim3(BB * QSPLIT), dim3(256), 0, stream>>>(anchor, positive, negative,
                                                        ws_loss, ws_score, ws_idx, ws_valid);
    k_merge<<<dim3(1), dim3(1024), 0, stream>>>(ws_loss, ws_score, ws_idx, ws_valid,
                                                out_loss, ws_sel, out_hasvalid);
    k_gather<<<dim3(32, BB), dim3(256), 0, stream>>>(negative, ws_sel, out_hard_neg);
}

// Round 4
// 223.212 us; speedup vs baseline: 1.1916x; 1.1916x over previous
//
#include <hip/hip_runtime.h>
#include <math.h>

#define BB 1024
#define NN 1024
#define DD 64
#define MARGIN_V 0.5f
#define EPS_V 1e-6f
#define QSPLIT 8               // blocks per batch row in k_dist
#define QCOLS (NN / QSPLIT)    // 128 columns per block

typedef float f32x4 __attribute__((ext_vector_type(4)));

// ---------------------------------------------------------------------------
// Kernel 1: 8192 blocks = 8 per batch row (q covers cols [q*128, +128)).
//   256 threads = 16 lane-groups of 16; each group handles 8 columns
//   (2 per j-iter, 4 iters), with an explicit 2-deep register double-buffer:
//   iteration j+1's 6 float4 loads are issued before iteration j is consumed,
//   keeping ~12 wave-loads in flight (fix for the 4.0 TB/s MLP ceiling).
//   anchor/positive are read non-temporally (single use) so L3 keeps
//   `negative` resident for k_gather.
// ---------------------------------------------------------------------------
__global__ __launch_bounds__(256) void k_dist(const float* __restrict__ a,
                                              const float* __restrict__ p,
                                              const float* __restrict__ g,
                                              float* __restrict__ ws_loss,
                                              float* __restrict__ ws_score,
                                              int* __restrict__ ws_idx,
                                              int* __restrict__ ws_valid)
{
    const int blk  = blockIdx.x;       // 0..8191
    const int b    = blk >> 3;
    const int q    = blk & 7;
    const int tid  = threadIdx.x;
    const int lane = tid & 63;
    const int wave = tid >> 6;         // 0..3
    const int grp  = lane >> 4;        // 0..3
    const int gl   = lane & 15;        // lane within 16-lane group
    const int group = wave * 4 + grp;  // 0..15

    const size_t base  = (size_t)b * (NN * DD);
    const int    ncol0 = q * QCOLS + group;
    const size_t off00 = base + (size_t)ncol0 * DD + (size_t)gl * 4;

    float loss_acc   = 0.f;
    float best_score = -INFINITY;
    int   best_idx   = 0;
    int   any_valid  = 0;

    // prologue: load iteration 0 (columns ncol0, ncol0+16)
    f32x4 cA0 = __builtin_nontemporal_load((const f32x4*)(a + off00));
    f32x4 cP0 = __builtin_nontemporal_load((const f32x4*)(p + off00));
    f32x4 cG0 = *(const f32x4*)(g + off00);
    f32x4 cA1 = __builtin_nontemporal_load((const f32x4*)(a + off00 + 16 * DD));
    f32x4 cP1 = __builtin_nontemporal_load((const f32x4*)(p + off00 + 16 * DD));
    f32x4 cG1 = *(const f32x4*)(g + off00 + 16 * DD);

    #pragma unroll
    for (int j = 0; j < 4; ++j) {
        // issue next iteration's loads BEFORE consuming the current one
        f32x4 nA0, nP0, nG0, nA1, nP1, nG1;
        if (j < 3) {
            const size_t offn = off00 + (size_t)((j + 1) * 32) * DD;
            nA0 = __builtin_nontemporal_load((const f32x4*)(a + offn));
            nP0 = __builtin_nontemporal_load((const f32x4*)(p + offn));
            nG0 = *(const f32x4*)(g + offn);
            nA1 = __builtin_nontemporal_load((const f32x4*)(a + offn + 16 * DD));
            nP1 = __builtin_nontemporal_load((const f32x4*)(p + offn + 16 * DD));
            nG1 = *(const f32x4*)(g + offn + 16 * DD);
        }

        const int n0 = ncol0 + j * 32;
        const int n1 = n0 + 16;

        float dp0 = 0.f, dn0 = 0.f, dp1 = 0.f, dn1 = 0.f, t;
        #pragma unroll
        for (int e = 0; e < 4; ++e) {
            t = cA0[e] - cP0[e] + EPS_V; dp0 += t * t;
            t = cA0[e] - cG0[e] + EPS_V; dn0 += t * t;
            t = cA1[e] - cP1[e] + EPS_V; dp1 += t * t;
            t = cA1[e] - cG1[e] + EPS_V; dn1 += t * t;
        }

        // interleaved butterflies over the 16-lane group (independent chains)
        for (int m = 1; m < 16; m <<= 1) {
            dp0 += __shfl_xor(dp0, m, 64);
            dn0 += __shfl_xor(dn0, m, 64);
            dp1 += __shfl_xor(dp1, m, 64);
            dn1 += __shfl_xor(dn1, m, 64);
        }

        if (gl == 0) {
            {
                const float diff = MARGIN_V + sqrtf(dp0) - sqrtf(dn0);
                loss_acc += fmaxf(diff, 0.f);
                const bool valid = diff > 0.f;
                any_valid |= (int)valid;
                const float score = valid ? sqrtf(dn0) : -INFINITY;
                if (score > best_score) { best_score = score; best_idx = n0; }
            }
            {
                const float diff = MARGIN_V + sqrtf(dp1) - sqrtf(dn1);
                loss_acc += fmaxf(diff, 0.f);
                const bool valid = diff > 0.f;
                any_valid |= (int)valid;
                const float score = valid ? sqrtf(dn1) : -INFINITY;
                if (score > best_score) { best_score = score; best_idx = n1; }
            }
        }

        if (j < 3) {
            cA0 = nA0; cP0 = nP0; cG0 = nG0;
            cA1 = nA1; cP1 = nP1; cG1 = nG1;
        }
    }

    __shared__ float s_score[16];
    __shared__ int   s_idx[16];
    __shared__ float s_loss[16];
    __shared__ int   s_valid[16];
    if (gl == 0) {
        s_score[group] = best_score;
        s_idx[group]   = best_idx;
        s_loss[group]  = loss_acc;
        s_valid[group] = any_valid;
    }
    __syncthreads();
    if (tid == 0) {
        float bs = s_score[0]; int bi = s_idx[0];
        float ls = s_loss[0];  int av = s_valid[0];
        for (int k = 1; k < 16; ++k) {
            const float sc = s_score[k]; const int ix = s_idx[k];
            if (sc > bs || (sc == bs && ix < bi)) { bs = sc; bi = ix; }
            ls += s_loss[k];
            av |= s_valid[k];
        }
        ws_loss[blk]  = ls;
        ws_score[blk] = bs;
        ws_idx[blk]   = bi;
        ws_valid[blk] = av;
    }
}

// ---------------------------------------------------------------------------
// Kernel 2 (single block, 1024 threads): thread b merges its 8 partials
// (first-index tie-break), writes sel/has_valid, block-reduces loss -> mean.
// ---------------------------------------------------------------------------
__global__ __launch_bounds__(1024) void k_merge(const float* __restrict__ ws_loss,
                                                const float* __restrict__ ws_score,
                                                const int* __restrict__ ws_idx,
                                                const int* __restrict__ ws_valid,
                                                float* __restrict__ out_loss,
                                                int* __restrict__ ws_sel,
                                                float* __restrict__ out_hasvalid)
{
    const int b = threadIdx.x;
    float ls = 0.f;
    float bs = -INFINITY;
    int   bi = 0x7fffffff;
    int   av = 0;
    for (int qq = 0; qq < QSPLIT; ++qq) {
        const int idx = b * QSPLIT + qq;
        const float sc = ws_score[idx];
        const int   ix = ws_idx[idx];
        if (sc > bs || (sc == bs && ix < bi)) { bs = sc; bi = ix; }
        ls += ws_loss[idx];
        av |= ws_valid[idx];
    }
    ws_sel[b] = bi;
    out_hasvalid[b] = av ? 1.0f : 0.0f;

    __shared__ float s[16];
    float v = ls;
    for (int m = 1; m < 64; m <<= 1) v += __shfl_xor(v, m, 64);
    if ((b & 63) == 0) s[b >> 6] = v;
    __syncthreads();
    if (b == 0) {
        float tot = 0.f;
        for (int k = 0; k < 16; ++k) tot += s[k];
        out_loss[0] = tot / (float)((size_t)BB * NN);
    }
}

// ---------------------------------------------------------------------------
// Kernel 3: hard_neg[b] = negative[sel_col[b]].  Scalar coalesced copies
// (dst is 4B-misaligned vs 16B). Non-temporal stores: output never re-read,
// keeps L3 for `negative`.
// ---------------------------------------------------------------------------
__global__ __launch_bounds__(256) void k_gather(const float* __restrict__ g,
                                                const int* __restrict__ ws_sel,
                                                float* __restrict__ out_hn)
{
    const int b   = blockIdx.y;
    const int sel = ws_sel[b];
    const float* __restrict__ src = g      + (size_t)sel * (NN * DD);
    float* __restrict__       dst = out_hn + (size_t)b   * (NN * DD);
    const int t = blockIdx.x * blockDim.x + threadIdx.x;   // 0..8191
    #pragma unroll
    for (int k = 0; k < (NN * DD) / 8192; ++k) {
        const int idx = t + k * 8192;
        __builtin_nontemporal_store(src[idx], dst + idx);
    }
}

extern "C" void kernel_launch(void* const* d_in, const int* in_sizes, int n_in,
                              void* d_out, int out_size, void* d_ws, size_t ws_size,
                              hipStream_t stream) {
    const float* anchor   = (const float*)d_in[0];
    const float* positive = (const float*)d_in[1];
    const float* negative = (const float*)d_in[2];
    float* out = (float*)d_out;

    // out layout: [0] loss | [1 .. 1+B*N*D) hard_neg | [1+B*N*D .. +B) has_valid
    float* out_loss     = out;
    float* out_hard_neg = out + 1;
    float* out_hasvalid = out + 1 + (size_t)BB * NN * DD;

    // ws layout: 8192 loss | 8192 score | 8192 idx | 8192 valid | 1024 sel
    float* ws_loss  = (float*)d_ws;
    float* ws_score = ws_loss + BB * QSPLIT;
    int*   ws_idx   = (int*)(ws_score + BB * QSPLIT);
    int*   ws_valid = ws_idx + BB * QSPLIT;
    int*   ws_sel   = ws_valid + BB * QSPLIT;

    k_dist<<<dim3(BB * QSPLIT), dim3(256), 0, stream>>>(anchor, positive, negative,
                                                        ws_loss, ws_score, ws_idx, ws_valid);
    k_merge<<<dim3(1), dim3(1024), 0, stream>>>(ws_loss, ws_score, ws_idx, ws_valid,
                                                out_loss, ws_sel, out_hasvalid);
    k_gather<<<dim3(32, BB), dim3(256), 0, stream>>>(negative, ws_sel, out_hard_neg);
}